// Round 1
// 4449.219 us; speedup vs baseline: 1.6340x; 1.6340x over previous
//
#include <hip/hip_runtime.h>

// ---------------------------------------------------------------------------
// GeneralRNN: h_t = hmlp([h_{t-1}, x_t]), y_t = ymlp(h_t)
// B=256, S=1024, D_IN=64, H=256, W_H=512, W_Y=256, D_OUT=64
//   K0 prep_pack: fp32 weights -> bf16 MFMA B-fragments in ws
//   K1 rnn_recur: 16 WGs x 512 thr, B_tile=16, MFMA 16x16x32 bf16.
//       This round: weight-resident recurrence.
//         W1h kc4..9 resident in VGPR (96 regs/wave); kc0..3 streamed from L2
//           via 2 rotating buffers, loads issued >=1 GEMM ahead.
//         W2h kc0..7 resident in VGPR (64 regs/wave); kc8..15 staged ONCE
//           into 128KB LDS (zero per-step global traffic).
//         x_{t+1} prefetched into regs during step t.
//         LDS strides 328/520 (row stride = 4 words mod 8) for bank balance.
//   K2 rnn_ymlp : 4096 WGs, parallel GEMM over all (b,t): y = ymlp(h).
// ---------------------------------------------------------------------------

typedef __bf16 bf16;
typedef __bf16 bf16x8 __attribute__((ext_vector_type(8)));
typedef float  f32x4  __attribute__((ext_vector_type(4)));

#define MFMA16(a, b, c) __builtin_amdgcn_mfma_f32_16x16x32_bf16((a), (b), (c), 0, 0, 0)

static constexpr int Bz = 256, Sq = 1024, DIN = 64, H = 256, WH = 512, WY = 256, DOUT = 64;
static constexpr int OUTS_N = Bz * Sq * DOUT;   // outs floats
static constexpr int HID_T  = Bz * H;           // floats per hiddens time slab

// packed bf16 fragment segments in ws (element offsets)
static constexpr int W1H_OFF = 0;
static constexpr int W1H_CNT = (H + DIN) * WH;          // [nt32][kc10][lane64][j8]
static constexpr int W2H_OFF = W1H_OFF + W1H_CNT;
static constexpr int W2H_CNT = WH * H;                  // [nt16][kc16][lane][j]
static constexpr int W1Y_OFF = W2H_OFF + W2H_CNT;
static constexpr int W1Y_CNT = H * WY;                  // [nt16][kc8][lane][j]
static constexpr int W2Y_OFF = W1Y_OFF + W1Y_CNT;
static constexpr int W2Y_CNT = WY * DOUT;               // [nt4][kc8][lane][j]
static constexpr int PACK_TOTAL = W2Y_OFF + W2Y_CNT;

// LDS row strides (bf16 elems). 328*2=656B and 520*2=1040B are 16B-aligned and
// give word-stride % 8 == 4 -> the 16-lane x stride b128 reads hit all banks
// evenly (old 336/528 had word-stride % 8 == 0 -> 4-way clumping).
static constexpr int HX_LD = 328;   // 320 + 8
static constexpr int A1_LD = 520;   // 512 + 8
static constexpr int HB_LD = 264;

__device__ __forceinline__ float silu_f(float z) {
    return z / (1.0f + __expf(-z));
}

// ---------------------------------------------------------------------------
// K0: pack all weights into bf16 B-fragment order.
// B-fragment for 16x16x32: lane L supplies B[k = (L>>4)*8 + j][n = L&15],
// stored as [ntile][kchunk][lane][j].
// ---------------------------------------------------------------------------
__global__ void prep_pack(const float* __restrict__ W1h, const float* __restrict__ W2h,
                          const float* __restrict__ W1y, const float* __restrict__ W2y,
                          bf16* __restrict__ ws) {
    int idx = blockIdx.x * 256 + threadIdx.x;
    if (idx >= PACK_TOTAL) return;
    int r = idx;
    const float* src; int row, col, ld;
    if (idx < W2H_OFF) {                               // W1h [320][512]
        int j = r & 7; r >>= 3; int L = r & 63; r >>= 6;
        int kc = r % 10, nt = r / 10;
        row = kc * 32 + ((L >> 4) << 3) + j; col = nt * 16 + (L & 15);
        src = W1h; ld = WH;
    } else if (idx < W1Y_OFF) {                        // W2h [512][256]
        r -= W2H_OFF;
        int j = r & 7; r >>= 3; int L = r & 63; r >>= 6;
        int kc = r & 15, nt = r >> 4;
        row = kc * 32 + ((L >> 4) << 3) + j; col = nt * 16 + (L & 15);
        src = W2h; ld = H;
    } else if (idx < W2Y_OFF) {                        // W1y [256][256]
        r -= W1Y_OFF;
        int j = r & 7; r >>= 3; int L = r & 63; r >>= 6;
        int kc = r & 7, nt = r >> 3;
        row = kc * 32 + ((L >> 4) << 3) + j; col = nt * 16 + (L & 15);
        src = W1y; ld = WY;
    } else {                                           // W2y [256][64]
        r -= W2Y_OFF;
        int j = r & 7; r >>= 3; int L = r & 63; r >>= 6;
        int kc = r & 7, nt = r >> 3;
        row = kc * 32 + ((L >> 4) << 3) + j; col = nt * 16 + (L & 15);
        src = W2y; ld = DOUT;
    }
    ws[idx] = (bf16)src[row * ld + col];
}

// ---------------------------------------------------------------------------
// K1: recurrence. grid=16, block=512 (8 waves), <=256 VGPR/wave (2 waves/EU).
// ---------------------------------------------------------------------------
__global__ __launch_bounds__(512, 2) void rnn_recur(
        const float* __restrict__ x, const float* __restrict__ b1h,
        const float* __restrict__ b2h, const bf16* __restrict__ ws,
        float* __restrict__ out) {
    // 131072 + 10496 + 16640 = 158208 B <= 163840 B LDS
    __shared__ __align__(16) bf16 w2l[16 * 8 * 64 * 8]; // W2h kc8..15 frags, 128KB
    __shared__ __align__(16) bf16 hx_s[16 * HX_LD];     // [batch16][h256 | x64]
    __shared__ __align__(16) bf16 a1_s[16 * A1_LD];     // [batch16][512]

    const int tid = threadIdx.x;
    const int wv = tid >> 6, ln = tid & 63;
    const int quad = ln >> 4, l16 = ln & 15;
    const int wgb = blockIdx.x;
    float* hid = out + OUTS_N;

    // h0 = 0: zero LDS h-region and hiddens[0] slab
    for (int i = tid; i < 16 * 256; i += 512) {
        int m = i >> 8, c = i & 255;
        hx_s[m * HX_LD + c] = (bf16)0.0f;
        hid[(wgb * 16 + m) * H + c] = 0.0f;
    }

    // stage W2h kc8..15 into LDS once: dst [nt16][kc8][lane][j8]
    for (int u = tid; u < 16 * 8 * 64; u += 512) {
        int nt = u >> 9, kc8 = (u >> 6) & 7, lu = u & 63;
        *(bf16x8*)(w2l + ((size_t)u << 3)) =
            *(const bf16x8*)(ws + W2H_OFF + (((nt * 16 + 8 + kc8) * 64 + lu) << 3));
    }

    // resident W1h kc4..9: wave wv owns ntiles {4wv..4wv+3} -> 96 VGPRs
    bf16x8 w1r[6][4];
#pragma unroll
    for (int kci = 0; kci < 6; kci++)
#pragma unroll
        for (int i = 0; i < 4; i++)
            w1r[kci][i] = *(const bf16x8*)(ws + W1H_OFF + ((((wv * 4 + i) * 10 + 4 + kci) * 64 + ln) << 3));

    // resident W2h kc0..7: wave wv owns ntiles {2wv, 2wv+1} -> 64 VGPRs
    bf16x8 w2f[8][2];
#pragma unroll
    for (int kc = 0; kc < 8; kc++)
#pragma unroll
        for (int i = 0; i < 2; i++)
            w2f[kc][i] = *(const bf16x8*)(ws + W2H_OFF + ((((wv * 2 + i) * 16 + kc) * 64 + ln) << 3));

    float bs1[4], bs2[2];
#pragma unroll
    for (int i = 0; i < 4; i++) bs1[i] = b1h[(wv * 4 + i) * 16 + l16];
#pragma unroll
    for (int i = 0; i < 2; i++) bs2[i] = b2h[(wv * 2 + i) * 16 + l16];

    // x staging role: thread -> (row m, 2 contiguous x elements)
    const int mrow = tid >> 5;
    const int i2 = (tid & 31) * 2;
    const float* xrow = x + (size_t)(wgb * 16 + mrow) * (Sq * DIN) + i2;

    // streamed W1h kc0..3 via two rotating 4-frag buffers (32 VGPRs)
#define W1HP(i, kc) ((const bf16x8*)(ws + W1H_OFF + ((((wv * 4 + (i)) * 10 + (kc)) * 64 + ln) << 3)))
    bf16x8 sA[4], sB[4];
#pragma unroll
    for (int i = 0; i < 4; i++) sA[i] = *W1HP(i, 0);
#pragma unroll
    for (int i = 0; i < 4; i++) sB[i] = *W1HP(i, 1);

    const f32x4 z4 = {0.0f, 0.0f, 0.0f, 0.0f};
    float2 xv = *(const float2*)(xrow);   // x_0 prefetched

#define LDHX(kc) (*(const bf16x8*)(hx_s + l16 * HX_LD + (kc) * 32 + quad * 8))
#define LDA1(kc) (*(const bf16x8*)(a1_s + l16 * A1_LD + (kc) * 32 + quad * 8))

#pragma unroll 1
    for (int t = 0; t < Sq; t++) {
        // stage prefetched x_t -> hx[:,256:320]
        hx_s[mrow * HX_LD + 256 + i2]     = (bf16)xv.x;
        hx_s[mrow * HX_LD + 256 + i2 + 1] = (bf16)xv.y;
        __syncthreads();   // (b): h + x staged, prior readers done

        // prefetch x_{t+1} (consumed at next loop top; full-step distance)
        xv = *(const float2*)(xrow + ((t + 1) & (Sq - 1)) * DIN);

        // ---- GEMM1: z1[16,512] = hx[16,320] @ W1h ----
        f32x4 acc1[4] = {z4, z4, z4, z4};
        bf16x8 a;
        // streamed kc0 (loaded >=1 full GEMM ago), then reload buffer -> kc2
        a = LDHX(0);
#pragma unroll
        for (int i = 0; i < 4; i++) acc1[i] = MFMA16(a, sA[i], acc1[i]);
#pragma unroll
        for (int i = 0; i < 4; i++) sA[i] = *W1HP(i, 2);
        a = LDHX(1);
#pragma unroll
        for (int i = 0; i < 4; i++) acc1[i] = MFMA16(a, sB[i], acc1[i]);
#pragma unroll
        for (int i = 0; i < 4; i++) sB[i] = *W1HP(i, 3);
        // resident kc4,kc5 while kc2/kc3 loads fly
        a = LDHX(4);
#pragma unroll
        for (int i = 0; i < 4; i++) acc1[i] = MFMA16(a, w1r[0][i], acc1[i]);
        a = LDHX(5);
#pragma unroll
        for (int i = 0; i < 4; i++) acc1[i] = MFMA16(a, w1r[1][i], acc1[i]);
        // streamed kc2, kc3
        a = LDHX(2);
#pragma unroll
        for (int i = 0; i < 4; i++) acc1[i] = MFMA16(a, sA[i], acc1[i]);
        a = LDHX(3);
#pragma unroll
        for (int i = 0; i < 4; i++) acc1[i] = MFMA16(a, sB[i], acc1[i]);
        // resident kc6..9
        a = LDHX(6);
#pragma unroll
        for (int i = 0; i < 4; i++) acc1[i] = MFMA16(a, w1r[2][i], acc1[i]);
        a = LDHX(7);
#pragma unroll
        for (int i = 0; i < 4; i++) acc1[i] = MFMA16(a, w1r[3][i], acc1[i]);
        a = LDHX(8);
#pragma unroll
        for (int i = 0; i < 4; i++) acc1[i] = MFMA16(a, w1r[4][i], acc1[i]);
        a = LDHX(9);
#pragma unroll
        for (int i = 0; i < 4; i++) acc1[i] = MFMA16(a, w1r[5][i], acc1[i]);

        // bias + silu -> a1 (bf16)
#pragma unroll
        for (int i = 0; i < 4; i++)
#pragma unroll
            for (int r = 0; r < 4; r++) {
                float s = silu_f(acc1[i][r] + bs1[i]);
                a1_s[(quad * 4 + r) * A1_LD + (wv * 4 + i) * 16 + l16] = (bf16)s;
            }
        __syncthreads();   // (d): a1 complete, hx readers done

        // issue next step's streamed kc0/kc1 now (distance ~= whole GEMM2)
#pragma unroll
        for (int i = 0; i < 4; i++) sA[i] = *W1HP(i, 0);
#pragma unroll
        for (int i = 0; i < 4; i++) sB[i] = *W1HP(i, 1);

        // ---- GEMM2: h[16,256] = a1[16,512] @ W2h ----
        f32x4 acc2[2] = {z4, z4};
#pragma unroll
        for (int kc = 0; kc < 8; kc++) {
            a = LDA1(kc);
#pragma unroll
            for (int i = 0; i < 2; i++) acc2[i] = MFMA16(a, w2f[kc][i], acc2[i]);
        }
#pragma unroll
        for (int kc = 8; kc < 16; kc++) {
            a = LDA1(kc);
#pragma unroll
            for (int i = 0; i < 2; i++) {
                bf16x8 b = *(const bf16x8*)(w2l + ((((wv * 2 + i) * 8 + (kc - 8)) * 64 + ln) << 3));
                acc2[i] = MFMA16(a, b, acc2[i]);
            }
        }

        // bias, write h: fp32 -> hiddens[t+1], bf16 -> LDS for next step
        float* hdst = hid + (size_t)(t + 1) * HID_T + (wgb * 16) * H;
#pragma unroll
        for (int i = 0; i < 2; i++)
#pragma unroll
            for (int r = 0; r < 4; r++) {
                float h = acc2[i][r] + bs2[i];
                int m = quad * 4 + r, c = (wv * 2 + i) * 16 + l16;
                hdst[m * H + c] = h;
                hx_s[m * HX_LD + c] = (bf16)h;
            }
        // no barrier: next x-stage writes hx[:,256:320] (disjoint); (b) guards reads
    }
#undef W1HP
#undef LDHX
#undef LDA1
}

// ---------------------------------------------------------------------------
// K2: output MLP over all (b,t). grid=4096 (b=g>>4, t0=(g&15)*64), block=256.
// ---------------------------------------------------------------------------
__global__ __launch_bounds__(256) void rnn_ymlp(
        const float* __restrict__ b1y, const float* __restrict__ b2y,
        const bf16* __restrict__ ws, float* __restrict__ out) {
    __shared__ __align__(16) bf16 hb[64 * HB_LD];   // h rows, later a2 rows

    const int tid = threadIdx.x, wv = tid >> 6, ln = tid & 63;
    const int quad = ln >> 4, l16 = ln & 15;
    const int g = blockIdx.x, b = g >> 4, t0 = (g & 15) * 64;
    const float* hid = out + OUTS_N;

    // stage h rows t0+1 .. t0+64 -> bf16 LDS
    {
        int r = tid >> 2, c0 = (tid & 3) * 64;
        const float* srcr = hid + (size_t)(t0 + 1 + r) * HID_T + b * H + c0;
        bf16* d0 = hb + r * HB_LD + c0;
#pragma unroll
        for (int jj = 0; jj < 16; jj++) {
            float4 v = *(const float4*)(srcr + jj * 4);
            bf16* d = d0 + jj * 4;
            d[0] = (bf16)v.x; d[1] = (bf16)v.y; d[2] = (bf16)v.z; d[3] = (bf16)v.w;
        }
    }
    __syncthreads();

    // GEMM1: z2[64,256] = hb @ W1y ; wave wv: ntiles {4wv..4wv+3}, mtiles 0..3
    const f32x4 z4 = {0.0f, 0.0f, 0.0f, 0.0f};
    f32x4 acc[4][4];
#pragma unroll
    for (int i = 0; i < 4; i++)
#pragma unroll
        for (int mt = 0; mt < 4; mt++) acc[i][mt] = z4;
#pragma unroll
    for (int kc = 0; kc < 8; kc++) {
        bf16x8 a[4];
#pragma unroll
        for (int mt = 0; mt < 4; mt++)
            a[mt] = *(const bf16x8*)(hb + (mt * 16 + l16) * HB_LD + kc * 32 + quad * 8);
#pragma unroll
        for (int i = 0; i < 4; i++) {
            bf16x8 bb = *(const bf16x8*)(ws + W1Y_OFF + ((((wv * 4 + i) * 8 + kc) * 64 + ln) << 3));
#pragma unroll
            for (int mt = 0; mt < 4; mt++) acc[i][mt] = MFMA16(a[mt], bb, acc[i][mt]);
        }
    }
    float bias1[4];
#pragma unroll
    for (int i = 0; i < 4; i++) bias1[i] = b1y[(wv * 4 + i) * 16 + l16];
    __syncthreads();   // all hb reads done before overwrite

    // silu -> a2 back into hb
#pragma unroll
    for (int i = 0; i < 4; i++)
#pragma unroll
        for (int mt = 0; mt < 4; mt++)
#pragma unroll
            for (int r = 0; r < 4; r++) {
                float s = silu_f(acc[i][mt][r] + bias1[i]);
                hb[(mt * 16 + quad * 4 + r) * HB_LD + (wv * 4 + i) * 16 + l16] = (bf16)s;
            }
    __syncthreads();

    // GEMM2: y[64,64] = a2 @ W2y ; wave wv owns ntile wv
    f32x4 acy[4] = {z4, z4, z4, z4};
#pragma unroll
    for (int kc = 0; kc < 8; kc++) {
        bf16x8 bb = *(const bf16x8*)(ws + W2Y_OFF + (((wv * 8 + kc) * 64 + ln) << 3));
#pragma unroll
        for (int mt = 0; mt < 4; mt++) {
            bf16x8 a = *(const bf16x8*)(hb + (mt * 16 + l16) * HB_LD + kc * 32 + quad * 8);
            acy[mt] = MFMA16(a, bb, acy[mt]);
        }
    }
    float bias2 = b2y[wv * 16 + l16];
    float* ob = out + (size_t)b * (Sq * DOUT);
#pragma unroll
    for (int mt = 0; mt < 4; mt++)
#pragma unroll
        for (int r = 0; r < 4; r++) {
            int m = mt * 16 + quad * 4 + r;
            ob[(t0 + m) * DOUT + wv * 16 + l16] = acy[mt][r] + bias2;
        }
}

// ---------------------------------------------------------------------------
extern "C" void kernel_launch(void* const* d_in, const int* in_sizes, int n_in,
                              void* d_out, int out_size, void* d_ws, size_t ws_size,
                              hipStream_t stream) {
    (void)in_sizes; (void)n_in; (void)out_size; (void)ws_size;
    const float* x   = (const float*)d_in[0];
    const float* W1h = (const float*)d_in[1];
    const float* b1h = (const float*)d_in[2];
    const float* W2h = (const float*)d_in[3];
    const float* b2h = (const float*)d_in[4];
    const float* W1y = (const float*)d_in[5];
    const float* b1y = (const float*)d_in[6];
    const float* W2y = (const float*)d_in[7];
    const float* b2y = (const float*)d_in[8];
    float* out = (float*)d_out;
    bf16* ws = (bf16*)d_ws;

    prep_pack<<<(PACK_TOTAL + 255) / 256, 256, 0, stream>>>(W1h, W2h, W1y, W2y, ws);
    rnn_recur<<<16, 512, 0, stream>>>(x, b1h, b2h, ws, out);
    rnn_ymlp<<<4096, 256, 0, stream>>>(b1y, b2y, ws, out);
}